// Round 4
// baseline (2497.981 us; speedup 1.0000x reference)
//
#include <hip/hip_runtime.h>
#include <math.h>

#define NIMG 12
#define NSZ 256
#define HWSZ 65536
#define NBLK 768

// tiled W layout: W[((n*64 + tile)*256 + u)*4 + slot], tile=(j&127)>>1, slot=(j&1)+((j>>7)<<1)
__device__ __forceinline__ size_t widx(int n, int u, int j)
{
  int tile = (j & 127) >> 1;
  int slot = (j & 1) + ((j >> 7) << 1);
  return ((((size_t)n << 6) + tile) << 10) + ((size_t)u << 2) + slot;
}

// ---------------- per-image flag barrier: 64 blocks, no RMW ----------------
__device__ __forceinline__ void isync(unsigned* flags, int base, int sr, unsigned gen)
{
  __syncthreads();
  int t = threadIdx.x;
  if (t < 64) {
    if (t == 0) {
      __builtin_amdgcn_fence(__ATOMIC_RELEASE, "agent");
      __hip_atomic_store(&flags[base + sr], gen, __ATOMIC_RELAXED, __HIP_MEMORY_SCOPE_AGENT);
    }
    unsigned v;
    do {
      v = __hip_atomic_load(&flags[base + t], __ATOMIC_RELAXED, __HIP_MEMORY_SCOPE_AGENT);
    } while (__any(v < gen));
    __builtin_amdgcn_fence(__ATOMIC_ACQUIRE, "agent");
  }
  __syncthreads();
}

// ---------------- 256-point Stockham FFT, one wave per transform ----------------
__device__ __forceinline__ void fft256g(float2* A, float2* B, const float2* tw, int lane,
                                        float dir, bool active)
{
  float2* src = A;
  float2* dst = B;
  int m = 1;
#pragma unroll
  for (int s = 0; s < 8; ++s) {
    __syncthreads();
    if (active) {
#pragma unroll
      for (int h = 0; h < 2; ++h) {
        int b = lane + (h << 6);
        int k = b & (m - 1);
        int jm = b - k;
        float2 a = src[b];
        float2 c = src[b + 128];
        float2 w = tw[jm];
        float wr = w.x, wi = dir * w.y;
        float ex = a.x - c.x, ey = a.y - c.y;
        dst[2 * jm + k]     = make_float2(a.x + c.x, a.y + c.y);
        dst[2 * jm + k + m] = make_float2(ex * wr - ey * wi, ex * wi + ey * wr);
      }
    }
    float2* t = src; src = dst; dst = t;
    m <<= 1;
  }
  __syncthreads();
}
__device__ __forceinline__ void fft256(float2* A, float2* B, const float2* tw, int lane, float dir)
{
  fft256g(A, B, tw, lane, dir, true);
}

__device__ __forceinline__ void make_tw(float2* tw, int t)
{
  float s, c;
  sincospif((float)t * (1.0f / 128.0f), &s, &c);
  tw[t] = make_float2(c, s);
}

__device__ __forceinline__ double fdval(const float2* tw, int k)
{
  return 2.0 - 2.0 * (double)tw[k].x;
}

// =======================================================================================
//            MEGA KERNEL — LDS-resident Fk/FkF/denq/D, tiled W, XCD-swizzled
// =======================================================================================
__global__ __launch_bounds__(256, 3) void k_mega(const float* __restrict__ sty,
                                                 const float* __restrict__ fkr,
                                                 const float* __restrict__ fki,
                                                 float2* __restrict__ WG,
                                                 float2* __restrict__ WF,
                                                 float* __restrict__ Dh,     // [2][NBLK*512]
                                                 float* __restrict__ x49,
                                                 float* __restrict__ out,
                                                 float cmom, unsigned* flags)
{
  __shared__ float2 tw[256];
  __shared__ float2 bufA[6][256];
  __shared__ float2 scrB[6][256];   // FFT scratch; unioned with aL/bL, Ml, dsA
  __shared__ float2 fkL[4][256];    // Fk for this block's 4 columns
  __shared__ float2 kfL[4][256];    // FkFSTy for this block's 4 columns
  __shared__ float  dnL[256];       // den for (u0 0..127) x (p 0..1)
  __shared__ float  D1L[4][256];
  __shared__ float  D2L[4][256];

  float*   aL   = (float*)scrB;               // [5][256] flat (phase A)
  float*   bL   = ((float*)scrB) + 5 * 256;   // [5][256] flat (phase A)
  double2* Ml   = (double2*)scrB;             // [2][128] flat (phase B)
  float*   dsAp = (float*)scrB;               // [2][128] flat (setup S2)

  int t = threadIdx.x;
  make_tw(tw, t);
  // XCD swizzle: physical bid -> xcd = bid&7; pack 96 consecutive slots per XCD
  int slot = ((blockIdx.x & 7) * 96) + (blockIdx.x >> 3);
  int n = slot >> 6;
  int sr = slot & 63;
  int fbase = n << 6;
  int r0 = sr << 2;
  int j0 = sr << 1;
  int w = t >> 6, lane = t & 63;
  const float sc = 1.0f / 65536.0f;
  size_t cb = ((((size_t)n << 6) + sr) << 10);   // this block's column tile base
  unsigned gen = 0;

  // ---------------- S1: row fwd FFT of STy rows r0..r0+3 -> WG (tiled); load fkL -------
  {
    const float* src = sty + (size_t)n * HWSZ + (size_t)(r0 + w) * NSZ;
#pragma unroll
    for (int q = 0; q < 4; ++q) { int j = lane + (q << 6); bufA[w][j] = make_float2(src[j], 0.f); }
    fft256(bufA[w], scrB[w], tw, lane, -1.f);
#pragma unroll
    for (int q = 0; q < 4; ++q) { int j = lane + (q << 6); WG[widx(n, r0 + w, j)] = bufA[w][j]; }
#pragma unroll
    for (int c = 0; c < 4; ++c) {
      int gc = j0 + (c & 1) + ((c >> 1) << 7);
      size_t idx = (size_t)n * HWSZ + (size_t)t * NSZ + gc;
      fkL[c][t] = make_float2(fkr[idx], fki[idx]);
    }
  }
  isync(flags, fbase, sr, ++gen);

  // ---------------- S2: col FFT, kfL, dnL, Fr0, col inv FFT -> WF (tiled) --------------
  {
#pragma unroll
    for (int q = 0; q < 4; ++q) { int u = lane + (q << 6); bufA[w][u] = WG[cb + (u << 2) + w]; }
    fft256(bufA[w], scrB[w], tw, lane, -1.f);
#pragma unroll
    for (int c = 0; c < 4; ++c) {
      float2 K = fkL[c][t];
      float2 f = bufA[c][t];
      kfL[c][t] = make_float2(K.x * f.x + K.y * f.y, K.x * f.y - K.y * f.x);
    }
    __syncthreads();
    {
      int u0 = t & 127, p = t >> 7;
      double s1 = 0.0, s2 = 0.0;
#pragma unroll
      for (int s = 0; s < 4; ++s) {
        int u = u0 + ((s & 1) << 7);
        int c = p + ((s >> 1) << 1);
        int gc = j0 + (c & 1) + ((c >> 1) << 7);
        double kr = fkL[c][u].x, ki = fkL[c][u].y;
        double k2 = kr * kr + ki * ki;
        double fd2 = fdval(tw, u) + fdval(tw, gc) + 1e-8;
        s1 += k2;
        s2 += k2 / fd2;
      }
      dnL[u0 * 2 + p] = (float)(s2 * 0.25 + 1e-6);
      dsAp[p * 128 + u0] = (float)(s1 * 0.25 + 1e-6);
    }
    __syncthreads();
#pragma unroll
    for (int c = 0; c < 4; ++c) {
      float d = dsAp[(c & 1) * 128 + (t & 127)];
      float2 kf = kfL[c][t];
      bufA[c][t] = make_float2(kf.x / d, kf.y / d);
    }
    fft256(bufA[w], scrB[w], tw, lane, +1.f);
#pragma unroll
    for (int q = 0; q < 4; ++q) { int u = lane + (q << 6); WF[cb + (u << 2) + w] = bufA[w][u]; }
  }
  isync(flags, fbase, sr, ++gen);

  // ---------------- main loop ----------------
  for (int k = 0; k < 50; ++k) {
    float gamp = (k >= 1) ? (float)(0.1 * exp2(-(double)(k - 1) / 50.0)) : 0.f;

    // ===== phase A: row inv FFT (6 rows incl halos) + shrink + G + row fwd FFT =====
    {
      int gr = (r0 + w - 1) & 255;
#pragma unroll
      for (int q = 0; q < 4; ++q) { int j = lane + (q << 6); bufA[w][j] = WF[widx(n, gr, j)]; }
      fft256(bufA[w], scrB[w], tw, lane, +1.f);
    }
    {
      bool act = (w < 2);
      int e = 4 + (w & 1);
      int gr = (r0 + e - 1) & 255;
      if (act) {
#pragma unroll
        for (int q = 0; q < 4; ++q) { int j = lane + (q << 6); bufA[e][j] = WF[widx(n, gr, j)]; }
      }
      fft256g(bufA[e], scrB[e], tw, lane, +1.f, act);
    }
    // shrink rows e=1..5 (global rows r0..r0+4); D in LDS, halo row via global ping-pong
    {
      int jm1 = (t - 1) & 255;
      size_t hR = (((size_t)n << 6) + ((sr + 1) & 63)) << 9;
      size_t hW = (((size_t)n << 6) + sr) << 9;
      const float* DhP = Dh + (size_t)((k + 1) & 1) * (NBLK * 512);   // parity (k-1)&1
      float* DhW = Dh + (size_t)(k & 1) * (NBLK * 512);
      for (int e = 1; e <= 5; ++e) {
        int gr = (r0 + e - 1) & 255;
        float xc = bufA[e][t].x * sc;
        if (k == 49 && e <= 4) x49[(size_t)n * HWSZ + (size_t)gr * NSZ + t] = xc;
        float a, b;
        if (k == 0) {
          a = xc; b = xc;
          if (e <= 4) { D1L[e - 1][t] = 0.f; D2L[e - 1][t] = 0.f; }
        } else {
          float dhr = xc - bufA[e][jm1].x * sc;
          float dvr = xc - bufA[e - 1][t].x * sc;
          float d1, d2;
          if (e <= 4) { d1 = D1L[e - 1][t]; d2 = D2L[e - 1][t]; }
          else        { d1 = DhP[hR + t];   d2 = DhP[hR + 256 + t]; }
          float nu1 = dhr + d1, nu2 = dvr + d2;
          float nu = sqrtf(nu1 * nu1 + nu2 * nu2 + 1e-8f);
          float A = fmaxf(0.f, nu - gamp) + 1e-8f;
          A = A / (A + gamp);
          float u1 = A * nu1, u2 = A * nu2;
          float d1v = d1 + dhr - u1;
          float d2v = d2 + dvr - u2;
          if (e <= 4) { D1L[e - 1][t] = d1v; D2L[e - 1][t] = d2v; }
          if (e == 1) { DhW[hW + t] = d1v; DhW[hW + 256 + t] = d2v; }
          a = u1 - d1v; b = u2 - d2v;
        }
        aL[(e - 1) * 256 + t] = a;
        bL[(e - 1) * 256 + t] = b;
      }
    }
    __syncthreads();
    {
#pragma unroll
      for (int q = 0; q < 4; ++q) {
        int j = lane + (q << 6);
        int jp1 = (j + 1) & 255;
        float g = aL[w * 256 + j] - aL[w * 256 + jp1] + bL[w * 256 + j] - bL[(w + 1) * 256 + j];
        bufA[w][j] = make_float2(g, 0.f);
      }
      fft256(bufA[w], scrB[w], tw, lane, -1.f);
#pragma unroll
      for (int q = 0; q < 4; ++q) { int j = lane + (q << 6); WG[widx(n, r0 + w, j)] = bufA[w][j]; }
    }
    isync(flags, fbase, sr, ++gen);

    // ===== phase B: col fwd FFT + freq pointwise (all LDS constants) + col inv FFT =====
    {
#pragma unroll
      for (int q = 0; q < 4; ++q) { int u = lane + (q << 6); bufA[w][u] = WG[cb + (u << 2) + w]; }
      fft256(bufA[w], scrB[w], tw, lane, -1.f);
#pragma unroll
      for (int c = 0; c < 4; ++c) {
        float2 kf = kfL[c][t];
        float2 fg = bufA[c][t];
        bufA[c][t] = make_float2(kf.x + 1e-6f * fg.x, kf.y + 1e-6f * fg.y);
      }
      __syncthreads();
      {
        int u0 = t & 127, p = t >> 7;
        double sx = 0.0, sy = 0.0;
#pragma unroll
        for (int s = 0; s < 4; ++s) {
          int u = u0 + ((s & 1) << 7);
          int c = p + ((s >> 1) << 1);
          int gc = j0 + (c & 1) + ((c >> 1) << 7);
          float2 f1 = bufA[c][u];
          double kr = fkL[c][u].x, ki = fkL[c][u].y;
          double fd2 = fdval(tw, u) + fdval(tw, gc) + 1e-8;
          sx += (kr * (double)f1.x - ki * (double)f1.y) / fd2;
          sy += (kr * (double)f1.y + ki * (double)f1.x) / fd2;
        }
        Ml[p * 128 + u0] = make_double2(sx * 0.25, sy * 0.25);
      }
      __syncthreads();
#pragma unroll
      for (int c = 0; c < 4; ++c) {
        int u = t;
        int gc = j0 + (c & 1) + ((c >> 1) << 7);
        float2 f1 = bufA[c][u];
        double2 m = Ml[(c & 1) * 128 + (u & 127)];
        double den = (double)dnL[(u & 127) * 2 + (c & 1)];
        double kr = fkL[c][u].x, ki = fkL[c][u].y;
        double px = (kr * m.x + ki * m.y) / den;
        double py = (kr * m.y - ki * m.x) / den;
        double fd2 = fdval(tw, u) + fdval(tw, gc) + 1e-8;
        double s2 = 1.0 / (1e-6 * fd2);
        bufA[c][u] = make_float2((float)(((double)f1.x - px) * s2),
                                 (float)(((double)f1.y - py) * s2));
      }
      fft256(bufA[w], scrB[w], tw, lane, +1.f);
#pragma unroll
      for (int q = 0; q < 4; ++q) { int u = lane + (q << 6); WF[cb + (u << 2) + w] = bufA[w][u]; }
    }
    isync(flags, fbase, sr, ++gen);
  }

  // ---------------- epilogue: final row inv FFT + momentum -> out ----------------
  {
    int gr = r0 + w;
#pragma unroll
    for (int q = 0; q < 4; ++q) { int j = lane + (q << 6); bufA[w][j] = WF[widx(n, gr, j)]; }
    fft256(bufA[w], scrB[w], tw, lane, +1.f);
    size_t base = (size_t)n * HWSZ + (size_t)gr * NSZ;
#pragma unroll
    for (int q = 0; q < 4; ++q) {
      int j = lane + (q << 6);
      float v = bufA[w][j].x * sc;
      out[base + j] = v + cmom * (v - x49[base + j]);
    }
  }
}

// =======================================================================================
//                     FALLBACK: round-0 multi-kernel path (proven correct)
// =======================================================================================
__global__ __launch_bounds__(256) void k_rowfwd_sty(const float* __restrict__ sty,
                                                    float2* __restrict__ Wb)
{
  __shared__ float2 tw[256];
  __shared__ float2 bufA[4][256];
  __shared__ float2 bufB[4][256];
  int t = threadIdx.x;
  make_tw(tw, t);
  int n = blockIdx.x >> 6;
  int r0 = (blockIdx.x & 63) << 2;
  int w = t >> 6, lane = t & 63;
  const float* src = sty + (size_t)n * HWSZ + (size_t)(r0 + w) * NSZ;
#pragma unroll
  for (int q = 0; q < 4; ++q) { int j = lane + (q << 6); bufA[w][j] = make_float2(src[j], 0.f); }
  fft256(bufA[w], bufB[w], tw, lane, -1.f);
  float2* dst = Wb + (size_t)n * HWSZ + (size_t)(r0 + w) * NSZ;
#pragma unroll
  for (int q = 0; q < 4; ++q) { int j = lane + (q << 6); dst[j] = bufA[w][j]; }
}

__global__ __launch_bounds__(256) void k_colsetup(float2* __restrict__ Wb,
                                                  float2* __restrict__ FkF,
                                                  const float* __restrict__ fkr,
                                                  const float* __restrict__ fki,
                                                  float* __restrict__ denq)
{
  __shared__ float2 tw[256];
  __shared__ float2 bufA[4][256];
  __shared__ float2 bufB[4][256];
  __shared__ float dsA[2][128];
  int t = threadIdx.x;
  make_tw(tw, t);
  int n = blockIdx.x >> 6;
  int j0 = (blockIdx.x & 63) << 1;
  int w = t >> 6, lane = t & 63;
  int gcw = j0 + (w & 1) + ((w >> 1) << 7);
  float2* Wn = Wb + (size_t)n * HWSZ;
#pragma unroll
  for (int q = 0; q < 4; ++q) { int u = lane + (q << 6); bufA[w][u] = Wn[(size_t)u * NSZ + gcw]; }
  fft256(bufA[w], bufB[w], tw, lane, -1.f);
#pragma unroll
  for (int c = 0; c < 4; ++c) {
    int u = t;
    int gc = j0 + (c & 1) + ((c >> 1) << 7);
    size_t idx = (size_t)n * HWSZ + (size_t)u * NSZ + gc;
    float kr = fkr[idx], ki = fki[idx];
    float2 f = bufA[c][u];
    float2 kf = make_float2(kr * f.x + ki * f.y, kr * f.y - ki * f.x);
    FkF[idx] = kf;
    bufA[c][u] = kf;
  }
  __syncthreads();
  {
    int u0 = t & 127, p = t >> 7;
    double s1 = 0.0, s2 = 0.0;
#pragma unroll
    for (int s = 0; s < 4; ++s) {
      int u = u0 + ((s & 1) << 7);
      int c = p + ((s >> 1) << 1);
      int gc = j0 + (c & 1) + ((c >> 1) << 7);
      size_t idx = (size_t)n * HWSZ + (size_t)u * NSZ + gc;
      double kr = fkr[idx], ki = fki[idx];
      double k2 = kr * kr + ki * ki;
      double fd2 = fdval(tw, u) + fdval(tw, gc) + 1e-8;
      s1 += k2;
      s2 += k2 / fd2;
    }
    denq[(size_t)n * 16384 + (size_t)u0 * 128 + (j0 + p)] = (float)(s2 * 0.25 + 1e-6);
    dsA[p][u0] = (float)(s1 * 0.25 + 1e-6);
  }
  __syncthreads();
#pragma unroll
  for (int c = 0; c < 4; ++c) {
    int u = t;
    float d = dsA[c & 1][u & 127];
    float2 kf = bufA[c][u];
    bufA[c][u] = make_float2(kf.x / d, kf.y / d);
  }
  fft256(bufA[w], bufB[w], tw, lane, +1.f);
#pragma unroll
  for (int q = 0; q < 4; ++q) { int u = lane + (q << 6); Wn[(size_t)u * NSZ + gcw] = bufA[w][u]; }
}

__global__ __launch_bounds__(256) void k_spatial_rowfwd(const float* __restrict__ x,
                                                        const float* __restrict__ D1p,
                                                        const float* __restrict__ D2p,
                                                        float* __restrict__ D1n,
                                                        float* __restrict__ D2n,
                                                        float2* __restrict__ Wb,
                                                        float gamp, int firstIter)
{
  __shared__ float2 tw[256];
  __shared__ float aL[5][256];
  __shared__ float bL[5][256];
  __shared__ float2 bufA[4][256];
  __shared__ float2 bufB[4][256];
  int t = threadIdx.x;
  make_tw(tw, t);
  int n = blockIdx.x >> 6;
  int r0 = (blockIdx.x & 63) << 2;
  const float* xn = x + (size_t)n * HWSZ;
  for (int rr = 0; rr < 5; ++rr) {
    int i = (r0 + rr) & 255;
    int im1 = (i - 1) & 255;
    int j = t;
    int jm1 = (j - 1) & 255;
    float xc = xn[(size_t)i * NSZ + j];
    float a, b;
    if (firstIter) {
      a = xc; b = xc;
    } else {
      float dhr = xc - xn[(size_t)i * NSZ + jm1];
      float dvr = xc - xn[(size_t)im1 * NSZ + j];
      size_t idx = (size_t)n * HWSZ + (size_t)i * NSZ + j;
      float d1 = D1p[idx], d2 = D2p[idx];
      float nu1 = dhr + d1, nu2 = dvr + d2;
      float nu = sqrtf(nu1 * nu1 + nu2 * nu2 + 1e-8f);
      float A = fmaxf(0.f, nu - gamp) + 1e-8f;
      A = A / (A + gamp);
      float u1 = A * nu1, u2 = A * nu2;
      float d1v = d1 + dhr - u1;
      float d2v = d2 + dvr - u2;
      if (rr < 4) { D1n[idx] = d1v; D2n[idx] = d2v; }
      a = u1 - d1v; b = u2 - d2v;
    }
    aL[rr][j] = a;
    bL[rr][j] = b;
  }
  __syncthreads();
  int w = t >> 6, lane = t & 63;
#pragma unroll
  for (int q = 0; q < 4; ++q) {
    int j = lane + (q << 6);
    int jp1 = (j + 1) & 255;
    float g = aL[w][j] - aL[w][jp1] + bL[w][j] - bL[w + 1][j];
    bufA[w][j] = make_float2(g, 0.f);
  }
  fft256(bufA[w], bufB[w], tw, lane, -1.f);
  float2* dst = Wb + (size_t)n * HWSZ + (size_t)(r0 + w) * NSZ;
#pragma unroll
  for (int q = 0; q < 4; ++q) { int j = lane + (q << 6); dst[j] = bufA[w][j]; }
}

__global__ __launch_bounds__(256) void k_colphase(float2* __restrict__ Wb,
                                                  const float2* __restrict__ FkF,
                                                  const float* __restrict__ fkr,
                                                  const float* __restrict__ fki,
                                                  const float* __restrict__ denq)
{
  __shared__ float2 tw[256];
  __shared__ float2 bufA[4][256];
  __shared__ float2 bufB[4][256];
  __shared__ double2 Ml[2][128];
  int t = threadIdx.x;
  make_tw(tw, t);
  int n = blockIdx.x >> 6;
  int j0 = (blockIdx.x & 63) << 1;
  int w = t >> 6, lane = t & 63;
  int gcw = j0 + (w & 1) + ((w >> 1) << 7);
  float2* Wn = Wb + (size_t)n * HWSZ;
#pragma unroll
  for (int q = 0; q < 4; ++q) { int u = lane + (q << 6); bufA[w][u] = Wn[(size_t)u * NSZ + gcw]; }
  fft256(bufA[w], bufB[w], tw, lane, -1.f);
#pragma unroll
  for (int c = 0; c < 4; ++c) {
    int u = t;
    int gc = j0 + (c & 1) + ((c >> 1) << 7);
    size_t idx = (size_t)n * HWSZ + (size_t)u * NSZ + gc;
    float2 kf = FkF[idx];
    float2 fg = bufA[c][u];
    bufA[c][u] = make_float2(kf.x + 1e-6f * fg.x, kf.y + 1e-6f * fg.y);
  }
  __syncthreads();
  {
    int u0 = t & 127, p = t >> 7;
    double sx = 0.0, sy = 0.0;
#pragma unroll
    for (int s = 0; s < 4; ++s) {
      int u = u0 + ((s & 1) << 7);
      int c = p + ((s >> 1) << 1);
      int gc = j0 + (c & 1) + ((c >> 1) << 7);
      size_t idx = (size_t)n * HWSZ + (size_t)u * NSZ + gc;
      float2 f1 = bufA[c][u];
      double kr = fkr[idx], ki = fki[idx];
      double fd2 = fdval(tw, u) + fdval(tw, gc) + 1e-8;
      sx += (kr * (double)f1.x - ki * (double)f1.y) / fd2;
      sy += (kr * (double)f1.y + ki * (double)f1.x) / fd2;
    }
    Ml[p][u0] = make_double2(sx * 0.25, sy * 0.25);
  }
  __syncthreads();
#pragma unroll
  for (int c = 0; c < 4; ++c) {
    int u = t;
    int gc = j0 + (c & 1) + ((c >> 1) << 7);
    size_t idx = (size_t)n * HWSZ + (size_t)u * NSZ + gc;
    float2 f1 = bufA[c][u];
    double2 m = Ml[c & 1][u & 127];
    double den = (double)denq[(size_t)n * 16384 + (size_t)(u & 127) * 128 + (j0 + (c & 1))];
    double kr = fkr[idx], ki = fki[idx];
    double px = (kr * m.x + ki * m.y) / den;
    double py = (kr * m.y - ki * m.x) / den;
    double fd2 = fdval(tw, u) + fdval(tw, gc) + 1e-8;
    double s2 = 1.0 / (1e-6 * fd2);
    bufA[c][u] = make_float2((float)(((double)f1.x - px) * s2),
                             (float)(((double)f1.y - py) * s2));
  }
  fft256(bufA[w], bufB[w], tw, lane, +1.f);
#pragma unroll
  for (int q = 0; q < 4; ++q) { int u = lane + (q << 6); Wn[(size_t)u * NSZ + gcw] = bufA[w][u]; }
}

__global__ __launch_bounds__(256) void k_rowinv(const float2* __restrict__ Wb,
                                                float* __restrict__ xout,
                                                const float* __restrict__ xold,
                                                float* __restrict__ pred,
                                                float cmom, int isLast)
{
  __shared__ float2 tw[256];
  __shared__ float2 bufA[4][256];
  __shared__ float2 bufB[4][256];
  int t = threadIdx.x;
  make_tw(tw, t);
  int n = blockIdx.x >> 6;
  int r0 = (blockIdx.x & 63) << 2;
  int w = t >> 6, lane = t & 63;
  const float2* src = Wb + (size_t)n * HWSZ + (size_t)(r0 + w) * NSZ;
#pragma unroll
  for (int q = 0; q < 4; ++q) { int j = lane + (q << 6); bufA[w][j] = src[j]; }
  fft256(bufA[w], bufB[w], tw, lane, +1.f);
  size_t base = (size_t)n * HWSZ + (size_t)(r0 + w) * NSZ;
#pragma unroll
  for (int q = 0; q < 4; ++q) {
    int j = lane + (q << 6);
    float v = bufA[w][j].x * (1.0f / 65536.0f);
    xout[base + j] = v;
    if (isLast) pred[base + j] = v + cmom * (v - xold[base + j]);
  }
}

// =======================================================================================
extern "C" void kernel_launch(void* const* d_in, const int* in_sizes, int n_in,
                              void* d_out, int out_size, void* d_ws, size_t ws_size,
                              hipStream_t stream)
{
  (void)in_sizes; (void)n_in; (void)out_size; (void)ws_size;
  const float* STy = (const float*)d_in[0];
  const float* fkr = (const float*)d_in[1];
  const float* fki = (const float*)d_in[2];
  float* out = (float*)d_out;

  char* p = (char*)d_ws;
  const size_t cplx = (size_t)NIMG * HWSZ * sizeof(float2);
  const size_t realb = (size_t)NIMG * HWSZ * sizeof(float);
  float2* WG  = (float2*)p; p += cplx;
  float2* WF  = (float2*)p; p += cplx;
  float2* FkF = (float2*)p; p += cplx;                          // fallback only
  float* denq = (float*)p;  p += (size_t)NIMG * 16384 * sizeof(float);  // fallback only
  float* D1a = (float*)p;   p += realb;                         // fallback only
  float* D2a = (float*)p;   p += realb;
  float* D1b = (float*)p;   p += realb;
  float* D2b = (float*)p;   p += realb;
  float* xA  = (float*)p;   p += realb;   // mega: x49 ; fallback: x0
  float* xB  = (float*)p;   p += realb;   // fallback: x1
  float* Dh  = (float*)p;   p += (size_t)2 * NBLK * 512 * sizeof(float);  // mega D halo
  unsigned* flags = (unsigned*)p; p += 4096;

  // host-side FISTA t sequence -> final momentum coefficient
  double t_old = 1.0, cm = 0.0;
  for (int k = 0; k < 50; ++k) {
    double t_new = (1.0 + sqrt(1.0 + 4.0 * t_old * t_old)) * 0.5;
    if (k == 49) cm = (t_old - 1.0) / t_new;
    t_old = t_new;
  }

  int maxb = 0;
  hipError_t oe = hipOccupancyMaxActiveBlocksPerMultiprocessor(&maxb, k_mega, 256, 0);
  bool coop = (oe == hipSuccess && maxb >= 3);

  dim3 grid(NBLK), blk(256);
  if (coop) {
    hipMemsetAsync(Dh, 0, (size_t)2 * NBLK * 512 * sizeof(float), stream);
    hipMemsetAsync(flags, 0, 4096, stream);
    k_mega<<<grid, blk, 0, stream>>>(STy, fkr, fki, WG, WF, Dh, xA, out, (float)cm, flags);
  } else {
    // proven round-0 path
    hipMemsetAsync(D1a, 0, 2 * realb, stream);
    float2* Wb = WG;
    float* x0 = xA; float* x1 = xB;
    k_rowfwd_sty<<<grid, blk, 0, stream>>>(STy, Wb);
    k_colsetup<<<grid, blk, 0, stream>>>(Wb, FkF, fkr, fki, denq);
    k_rowinv<<<grid, blk, 0, stream>>>(Wb, x0, x0, out, 0.f, 0);
    double to = 1.0;
    for (int k = 0; k < 50; ++k) {
      float gamp = (k >= 1) ? (float)(0.1 * exp2(-(double)(k - 1) / 50.0)) : 0.f;
      const float* xk = (k & 1) ? x1 : x0;
      float* xn = (k & 1) ? x0 : x1;
      const float* D1p = (k & 1) ? D1a : D1b;
      const float* D2p = (k & 1) ? D2a : D2b;
      float* D1w = (k & 1) ? D1b : D1a;
      float* D2w = (k & 1) ? D2b : D2a;
      k_spatial_rowfwd<<<grid, blk, 0, stream>>>(xk, D1p, D2p, D1w, D2w, Wb, gamp, (k == 0) ? 1 : 0);
      k_colphase<<<grid, blk, 0, stream>>>(Wb, FkF, fkr, fki, denq);
      double tn = (1.0 + sqrt(1.0 + 4.0 * to * to)) * 0.5;
      int isLast = (k == 49) ? 1 : 0;
      float cmom = (float)((to - 1.0) / tn);
      k_rowinv<<<grid, blk, 0, stream>>>(Wb, xn, xk, out, isLast ? cmom : 0.f, isLast);
      to = tn;
    }
  }
}

// Round 5
// 2484.707 us; speedup vs baseline: 1.0053x; 1.0053x over previous
//
#include <hip/hip_runtime.h>
#include <math.h>

#define NIMG 12
#define NSZ 256
#define HWSZ 65536
#define NBLK 768

// tiled W layout: W[((n*64 + tile)*256 + u)*4 + slot], tile=(j&127)>>1, slot=(j&1)+((j>>7)<<1)
__device__ __forceinline__ size_t widx(int n, int u, int j)
{
  int tile = (j & 127) >> 1;
  int slot = (j & 1) + ((j >> 7) << 1);
  return ((((size_t)n << 6) + tile) << 10) + ((size_t)u << 2) + slot;
}

// ---------------- per-image flag barrier: 64 blocks, no RMW, sleep backoff ----------------
__device__ __forceinline__ void isync(unsigned* flags, int base, int sr, unsigned gen)
{
  __syncthreads();
  int t = threadIdx.x;
  if (t < 64) {
    if (t == 0) {
      __builtin_amdgcn_fence(__ATOMIC_RELEASE, "agent");
      __hip_atomic_store(&flags[base + sr], gen, __ATOMIC_RELAXED, __HIP_MEMORY_SCOPE_AGENT);
    }
    unsigned v;
    int it = 0;
    do {
      if (it++ > 2) __builtin_amdgcn_s_sleep(4);
      v = __hip_atomic_load(&flags[base + t], __ATOMIC_RELAXED, __HIP_MEMORY_SCOPE_AGENT);
    } while (__any(v < gen));
    __builtin_amdgcn_fence(__ATOMIC_ACQUIRE, "agent");
  }
  __syncthreads();
}

// ================= radix-4 Stockham, wave-private (NO barriers inside) =================
// One stage: butterfly b (=lane) with parameter m; dst[4q+k+{0,m,2m,3m}], q=b-k, k=b&(m-1).
// Twiddles w1,w2,w3 = e^{+2pi i {q,2q,3q}/256}; dir applied to imag at use. c3 = dir*i*(x1-x3).
__device__ __forceinline__ void r4_bfly(const float2* __restrict__ S, float2* __restrict__ D,
                                        int b, int m, float2 w1, float2 w2, float2 w3,
                                        float dir, bool usetw)
{
  int k = b & (m - 1);
  int base = ((b - k) << 2) + k;
  float2 x0 = S[b], x1 = S[b + 64], x2 = S[b + 128], x3 = S[b + 192];
  float t0x = x0.x + x2.x, t0y = x0.y + x2.y;
  float t1x = x0.x - x2.x, t1y = x0.y - x2.y;
  float t2x = x1.x + x3.x, t2y = x1.y + x3.y;
  float e3x = x1.x - x3.x, e3y = x1.y - x3.y;
  float t3x = -dir * e3y, t3y = dir * e3x;
  D[base] = make_float2(t0x + t2x, t0y + t2y);
  float y1x = t1x + t3x, y1y = t1y + t3y;
  float y2x = t0x - t2x, y2y = t0y - t2y;
  float y3x = t1x - t3x, y3y = t1y - t3y;
  if (usetw) {
    float w1i = dir * w1.y, w2i = dir * w2.y, w3i = dir * w3.y;
    D[base + m]     = make_float2(y1x * w1.x - y1y * w1i, y1x * w1i + y1y * w1.x);
    D[base + 2 * m] = make_float2(y2x * w2.x - y2y * w2i, y2x * w2i + y2y * w2.x);
    D[base + 3 * m] = make_float2(y3x * w3.x - y3y * w3i, y3x * w3i + y3y * w3.x);
  } else {
    D[base + m]     = make_float2(y1x, y1y);
    D[base + 2 * m] = make_float2(y2x, y2y);
    D[base + 3 * m] = make_float2(y3x, y3y);
  }
}

struct Tw { float2 a1, a2, a3, b1, b2, b3, c1, c2, c3; };

__device__ __forceinline__ float2 mktw(int q)
{
  float s, c;
  sincospif((float)q * (1.0f / 128.0f), &s, &c);
  return make_float2(c, s);
}

// full 256-pt FFT of one row (wave-private: caller guarantees this wave owns A,B)
__device__ __forceinline__ void fft4_row(float2* A, float2* B, int lane, float dir, const Tw& tw)
{
  r4_bfly(A, B, lane, 1,  tw.a1, tw.a2, tw.a3, dir, true);
  r4_bfly(B, A, lane, 4,  tw.b1, tw.b2, tw.b3, dir, true);
  r4_bfly(A, B, lane, 16, tw.c1, tw.c2, tw.c3, dir, true);
  r4_bfly(B, A, lane, 64, tw.a1, tw.a1, tw.a1, dir, false);   // q=0: no twiddle
}

// =======================================================================================
//            MEGA KERNEL — radix-4 reg-twiddle FFT, LDS constants, tiled W
// =======================================================================================
__global__ __launch_bounds__(256, 3) void k_mega(const float* __restrict__ sty,
                                                 const float* __restrict__ fkr,
                                                 const float* __restrict__ fki,
                                                 float2* __restrict__ WG,
                                                 float2* __restrict__ WF,
                                                 float* __restrict__ Dh,     // [2][NBLK*512]
                                                 float* __restrict__ x49,
                                                 float* __restrict__ out,
                                                 float cmom, unsigned* flags)
{
  __shared__ __align__(16) float2 bufA[6][256];
  __shared__ __align__(16) float2 scrB[6][256];   // FFT scratch; union aL/bL, Ml, dsA
  __shared__ float2 fkL[4][256];
  __shared__ float2 kfL[4][256];
  __shared__ float  dnL[256];
  __shared__ float  D1L[4][256];
  __shared__ float  D2L[4][256];

  float*   aL   = (float*)scrB;
  float*   bL   = ((float*)scrB) + 5 * 256;
  double2* Ml   = (double2*)scrB;
  float*   dsAp = (float*)scrB;

  int t = threadIdx.x;
  int slot = ((blockIdx.x & 7) * 96) + (blockIdx.x >> 3);
  int n = slot >> 6;
  int sr = slot & 63;
  int fbase = n << 6;
  int r0 = sr << 2;
  int j0 = sr << 1;
  int w = t >> 6, lane = t & 63;
  const float sc = 1.0f / 65536.0f;
  size_t cb = ((((size_t)n << 6) + sr) << 10);
  unsigned gen = 0;

  // per-lane register twiddles (stage m=1: q=lane; m=4; m=16)
  Tw tw;
  {
    int qa = lane, qb = lane & ~3, qc = lane & ~15;
    tw.a1 = mktw(qa);  tw.a2 = mktw(2 * qa); tw.a3 = mktw(3 * qa);
    tw.b1 = mktw(qb);  tw.b2 = mktw(2 * qb); tw.b3 = mktw(3 * qb);
    tw.c1 = mktw(qc);  tw.c2 = mktw(2 * qc); tw.c3 = mktw(3 * qc);
  }
  // f64 reciprocals for the frequency pointwise (loop-invariant, per-thread positions)
  int u0 = t & 127, pp = t >> 7;
  double fdgc[4], rM[4], rF[4];
  double rdn0, rdn1;
  {
    double s;
    s = sinpi((double)u0 * (1.0 / 256.0));        double fdu0 = 4.0 * s * s;
    s = sinpi((double)(u0 + 128) * (1.0 / 256.0)); double fdu1 = 4.0 * s * s;
#pragma unroll
    for (int c = 0; c < 4; ++c) {
      int gc = j0 + (c & 1) + ((c >> 1) << 7);
      s = sinpi((double)gc * (1.0 / 256.0));
      fdgc[c] = 4.0 * s * s;
    }
#pragma unroll
    for (int s4 = 0; s4 < 4; ++s4) {
      double fdu = (s4 & 1) ? fdu1 : fdu0;
      rM[s4] = 1.0 / (fdu + fdgc[pp + ((s4 >> 1) << 1)] + 1e-8);
    }
    double fdt = pp ? fdu1 : fdu0;                // fd(t), t = u0 + 128*pp
#pragma unroll
    for (int c = 0; c < 4; ++c) rF[c] = 1.0 / (fdt + fdgc[c] + 1e-8);
  }

  // ---------------- S1: row fwd FFT of STy rows r0..r0+3 -> WG; load fkL ----------------
  {
    const float* src = sty + (size_t)n * HWSZ + (size_t)(r0 + w) * NSZ;
#pragma unroll
    for (int q = 0; q < 4; ++q) { int j = lane + (q << 6); bufA[w][j] = make_float2(src[j], 0.f); }
    fft4_row(bufA[w], scrB[w], lane, -1.f, tw);
#pragma unroll
    for (int q = 0; q < 4; ++q) { int j = lane + (q << 6); WG[widx(n, r0 + w, j)] = bufA[w][j]; }
#pragma unroll
    for (int c = 0; c < 4; ++c) {
      int gc = j0 + (c & 1) + ((c >> 1) << 7);
      size_t idx = (size_t)n * HWSZ + (size_t)t * NSZ + gc;
      fkL[c][t] = make_float2(fkr[idx], fki[idx]);
    }
  }
  isync(flags, fbase, sr, ++gen);

  // ---------------- S2: col FFT, kfL, dnL, Fr0, col inv FFT -> WF ----------------
  {
#pragma unroll
    for (int q = 0; q < 4; ++q) { int u = lane + (q << 6); bufA[w][u] = WG[cb + (u << 2) + w]; }
    fft4_row(bufA[w], scrB[w], lane, -1.f, tw);
    __syncthreads();
#pragma unroll
    for (int c = 0; c < 4; ++c) {
      float2 K = fkL[c][t];
      float2 f = bufA[c][t];
      kfL[c][t] = make_float2(K.x * f.x + K.y * f.y, K.x * f.y - K.y * f.x);
    }
    {
      double s1 = 0.0, s2 = 0.0;
#pragma unroll
      for (int s4 = 0; s4 < 4; ++s4) {
        int u = u0 + ((s4 & 1) << 7);
        int c = pp + ((s4 >> 1) << 1);
        double kr = fkL[c][u].x, ki = fkL[c][u].y;
        double k2 = kr * kr + ki * ki;
        s1 += k2;
        s2 += k2 * rM[s4];
      }
      dnL[u0 * 2 + pp] = (float)(s2 * 0.25 + 1e-6);
      dsAp[pp * 128 + u0] = (float)(s1 * 0.25 + 1e-6);
    }
    __syncthreads();
    rdn0 = 1.0 / (double)dnL[u0 * 2];
    rdn1 = 1.0 / (double)dnL[u0 * 2 + 1];
#pragma unroll
    for (int c = 0; c < 4; ++c) {
      float d = dsAp[(c & 1) * 128 + u0];
      float2 kf = kfL[c][t];
      bufA[c][t] = make_float2(kf.x / d, kf.y / d);
    }
    __syncthreads();
    fft4_row(bufA[w], scrB[w], lane, +1.f, tw);
#pragma unroll
    for (int q = 0; q < 4; ++q) { int u = lane + (q << 6); WF[cb + (u << 2) + w] = bufA[w][u]; }
  }
  isync(flags, fbase, sr, ++gen);

  // ---------------- main loop ----------------
  for (int k = 0; k < 50; ++k) {
    float gamp = (k >= 1) ? (float)(0.1 * exp2(-(double)(k - 1) / 50.0)) : 0.f;

    // ===== phase A: row inv FFT (6 rows incl halos) + shrink + G + row fwd FFT =====
    {
      int gr = (r0 + w - 1) & 255;
#pragma unroll
      for (int q = 0; q < 4; ++q) { int j = lane + (q << 6); bufA[w][j] = WF[widx(n, gr, j)]; }
      fft4_row(bufA[w], scrB[w], lane, +1.f, tw);
      if (w < 2) {
        int e = 4 + w;
        int gr2 = (r0 + e - 1) & 255;
#pragma unroll
        for (int q = 0; q < 4; ++q) { int j = lane + (q << 6); bufA[e][j] = WF[widx(n, gr2, j)]; }
        fft4_row(bufA[e], scrB[e], lane, +1.f, tw);
      }
    }
    __syncthreads();
    // shrink rows e=1..5 (global rows r0..r0+4); D in LDS, halo row via global ping-pong
    {
      int jm1 = (t - 1) & 255;
      size_t hR = (((size_t)n << 6) + ((sr + 1) & 63)) << 9;
      size_t hW = (((size_t)n << 6) + sr) << 9;
      const float* DhP = Dh + (size_t)((k + 1) & 1) * (NBLK * 512);
      float* DhW = Dh + (size_t)(k & 1) * (NBLK * 512);
      for (int e = 1; e <= 5; ++e) {
        int gr = (r0 + e - 1) & 255;
        float xc = bufA[e][t].x * sc;
        if (k == 49 && e <= 4) x49[(size_t)n * HWSZ + (size_t)gr * NSZ + t] = xc;
        float a, b;
        if (k == 0) {
          a = xc; b = xc;
          if (e <= 4) { D1L[e - 1][t] = 0.f; D2L[e - 1][t] = 0.f; }
        } else {
          float dhr = xc - bufA[e][jm1].x * sc;
          float dvr = xc - bufA[e - 1][t].x * sc;
          float d1, d2;
          if (e <= 4) { d1 = D1L[e - 1][t]; d2 = D2L[e - 1][t]; }
          else        { d1 = DhP[hR + t];   d2 = DhP[hR + 256 + t]; }
          float nu1 = dhr + d1, nu2 = dvr + d2;
          float nu = sqrtf(nu1 * nu1 + nu2 * nu2 + 1e-8f);
          float A = fmaxf(0.f, nu - gamp) + 1e-8f;
          A = A / (A + gamp);
          float u1 = A * nu1, u2 = A * nu2;
          float d1v = d1 + dhr - u1;
          float d2v = d2 + dvr - u2;
          if (e <= 4) { D1L[e - 1][t] = d1v; D2L[e - 1][t] = d2v; }
          if (e == 1) { DhW[hW + t] = d1v; DhW[hW + 256 + t] = d2v; }
          a = u1 - d1v; b = u2 - d2v;
        }
        aL[(e - 1) * 256 + t] = a;
        bL[(e - 1) * 256 + t] = b;
      }
    }
    __syncthreads();
    {
#pragma unroll
      for (int q = 0; q < 4; ++q) {
        int j = lane + (q << 6);
        int jp1 = (j + 1) & 255;
        float g = aL[w * 256 + j] - aL[w * 256 + jp1] + bL[w * 256 + j] - bL[(w + 1) * 256 + j];
        bufA[w][j] = make_float2(g, 0.f);
      }
      fft4_row(bufA[w], scrB[w], lane, -1.f, tw);
#pragma unroll
      for (int q = 0; q < 4; ++q) { int j = lane + (q << 6); WG[widx(n, r0 + w, j)] = bufA[w][j]; }
    }
    isync(flags, fbase, sr, ++gen);

    // ===== phase B: col fwd FFT + freq pointwise (reg/LDS constants) + col inv FFT =====
    {
#pragma unroll
      for (int q = 0; q < 4; ++q) { int u = lane + (q << 6); bufA[w][u] = WG[cb + (u << 2) + w]; }
      fft4_row(bufA[w], scrB[w], lane, -1.f, tw);
      __syncthreads();
#pragma unroll
      for (int c = 0; c < 4; ++c) {
        float2 kf = kfL[c][t];
        float2 fg = bufA[c][t];
        bufA[c][t] = make_float2(kf.x + 1e-6f * fg.x, kf.y + 1e-6f * fg.y);
      }
      __syncthreads();
      {
        double sx = 0.0, sy = 0.0;
#pragma unroll
        for (int s4 = 0; s4 < 4; ++s4) {
          int u = u0 + ((s4 & 1) << 7);
          int c = pp + ((s4 >> 1) << 1);
          float2 f1 = bufA[c][u];
          double kr = fkL[c][u].x, ki = fkL[c][u].y;
          sx += (kr * (double)f1.x - ki * (double)f1.y) * rM[s4];
          sy += (kr * (double)f1.y + ki * (double)f1.x) * rM[s4];
        }
        Ml[pp * 128 + u0] = make_double2(sx * 0.25, sy * 0.25);
      }
      __syncthreads();
#pragma unroll
      for (int c = 0; c < 4; ++c) {
        float2 f1 = bufA[c][t];
        double2 m = Ml[(c & 1) * 128 + u0];
        double rden = (c & 1) ? rdn1 : rdn0;
        double kr = fkL[c][t].x, ki = fkL[c][t].y;
        double px = (kr * m.x + ki * m.y) * rden;
        double py = (kr * m.y - ki * m.x) * rden;
        double s2 = 1e6 * rF[c];
        bufA[c][t] = make_float2((float)(((double)f1.x - px) * s2),
                                 (float)(((double)f1.y - py) * s2));
      }
      __syncthreads();
      fft4_row(bufA[w], scrB[w], lane, +1.f, tw);
#pragma unroll
      for (int q = 0; q < 4; ++q) { int u = lane + (q << 6); WF[cb + (u << 2) + w] = bufA[w][u]; }
    }
    isync(flags, fbase, sr, ++gen);
  }

  // ---------------- epilogue: final row inv FFT + momentum -> out ----------------
  {
    int gr = r0 + w;
#pragma unroll
    for (int q = 0; q < 4; ++q) { int j = lane + (q << 6); bufA[w][j] = WF[widx(n, gr, j)]; }
    fft4_row(bufA[w], scrB[w], lane, +1.f, tw);
    size_t base = (size_t)n * HWSZ + (size_t)gr * NSZ;
#pragma unroll
    for (int q = 0; q < 4; ++q) {
      int j = lane + (q << 6);
      float v = bufA[w][j].x * sc;
      out[base + j] = v + cmom * (v - x49[base + j]);
    }
  }
}

// =======================================================================================
//                     FALLBACK: round-0 multi-kernel path (proven correct)
// =======================================================================================
__device__ __forceinline__ void fft256g(float2* A, float2* B, const float2* twl, int lane,
                                        float dir, bool active)
{
  float2* src = A;
  float2* dst = B;
  int m = 1;
#pragma unroll
  for (int s = 0; s < 8; ++s) {
    __syncthreads();
    if (active) {
#pragma unroll
      for (int h = 0; h < 2; ++h) {
        int b = lane + (h << 6);
        int k = b & (m - 1);
        int jm = b - k;
        float2 a = src[b];
        float2 c = src[b + 128];
        float2 wv = twl[jm];
        float wr = wv.x, wi = dir * wv.y;
        float ex = a.x - c.x, ey = a.y - c.y;
        dst[2 * jm + k]     = make_float2(a.x + c.x, a.y + c.y);
        dst[2 * jm + k + m] = make_float2(ex * wr - ey * wi, ex * wi + ey * wr);
      }
    }
    float2* t = src; src = dst; dst = t;
    m <<= 1;
  }
  __syncthreads();
}
__device__ __forceinline__ void fft256(float2* A, float2* B, const float2* twl, int lane, float dir)
{
  fft256g(A, B, twl, lane, dir, true);
}
__device__ __forceinline__ void make_tw(float2* twl, int t)
{
  float s, c;
  sincospif((float)t * (1.0f / 128.0f), &s, &c);
  twl[t] = make_float2(c, s);
}
__device__ __forceinline__ double fdval(const float2* twl, int k)
{
  return 2.0 - 2.0 * (double)twl[k].x;
}

__global__ __launch_bounds__(256) void k_rowfwd_sty(const float* __restrict__ sty,
                                                    float2* __restrict__ Wb)
{
  __shared__ float2 twl[256];
  __shared__ float2 bufA[4][256];
  __shared__ float2 bufB[4][256];
  int t = threadIdx.x;
  make_tw(twl, t);
  int n = blockIdx.x >> 6;
  int r0 = (blockIdx.x & 63) << 2;
  int w = t >> 6, lane = t & 63;
  const float* src = sty + (size_t)n * HWSZ + (size_t)(r0 + w) * NSZ;
#pragma unroll
  for (int q = 0; q < 4; ++q) { int j = lane + (q << 6); bufA[w][j] = make_float2(src[j], 0.f); }
  fft256(bufA[w], bufB[w], twl, lane, -1.f);
  float2* dst = Wb + (size_t)n * HWSZ + (size_t)(r0 + w) * NSZ;
#pragma unroll
  for (int q = 0; q < 4; ++q) { int j = lane + (q << 6); dst[j] = bufA[w][j]; }
}

__global__ __launch_bounds__(256) void k_colsetup(float2* __restrict__ Wb,
                                                  float2* __restrict__ FkF,
                                                  const float* __restrict__ fkr,
                                                  const float* __restrict__ fki,
                                                  float* __restrict__ denq)
{
  __shared__ float2 twl[256];
  __shared__ float2 bufA[4][256];
  __shared__ float2 bufB[4][256];
  __shared__ float dsA[2][128];
  int t = threadIdx.x;
  make_tw(twl, t);
  int n = blockIdx.x >> 6;
  int j0 = (blockIdx.x & 63) << 1;
  int w = t >> 6, lane = t & 63;
  int gcw = j0 + (w & 1) + ((w >> 1) << 7);
  float2* Wn = Wb + (size_t)n * HWSZ;
#pragma unroll
  for (int q = 0; q < 4; ++q) { int u = lane + (q << 6); bufA[w][u] = Wn[(size_t)u * NSZ + gcw]; }
  fft256(bufA[w], bufB[w], twl, lane, -1.f);
#pragma unroll
  for (int c = 0; c < 4; ++c) {
    int u = t;
    int gc = j0 + (c & 1) + ((c >> 1) << 7);
    size_t idx = (size_t)n * HWSZ + (size_t)u * NSZ + gc;
    float kr = fkr[idx], ki = fki[idx];
    float2 f = bufA[c][u];
    float2 kf = make_float2(kr * f.x + ki * f.y, kr * f.y - ki * f.x);
    FkF[idx] = kf;
    bufA[c][u] = kf;
  }
  __syncthreads();
  {
    int u0 = t & 127, p = t >> 7;
    double s1 = 0.0, s2 = 0.0;
#pragma unroll
    for (int s = 0; s < 4; ++s) {
      int u = u0 + ((s & 1) << 7);
      int c = p + ((s >> 1) << 1);
      int gc = j0 + (c & 1) + ((c >> 1) << 7);
      size_t idx = (size_t)n * HWSZ + (size_t)u * NSZ + gc;
      double kr = fkr[idx], ki = fki[idx];
      double k2 = kr * kr + ki * ki;
      double fd2 = fdval(twl, u) + fdval(twl, gc) + 1e-8;
      s1 += k2;
      s2 += k2 / fd2;
    }
    denq[(size_t)n * 16384 + (size_t)u0 * 128 + (j0 + p)] = (float)(s2 * 0.25 + 1e-6);
    dsA[p][u0] = (float)(s1 * 0.25 + 1e-6);
  }
  __syncthreads();
#pragma unroll
  for (int c = 0; c < 4; ++c) {
    int u = t;
    float d = dsA[c & 1][u & 127];
    float2 kf = bufA[c][u];
    bufA[c][u] = make_float2(kf.x / d, kf.y / d);
  }
  fft256(bufA[w], bufB[w], twl, lane, +1.f);
#pragma unroll
  for (int q = 0; q < 4; ++q) { int u = lane + (q << 6); Wn[(size_t)u * NSZ + gcw] = bufA[w][u]; }
}

__global__ __launch_bounds__(256) void k_spatial_rowfwd(const float* __restrict__ x,
                                                        const float* __restrict__ D1p,
                                                        const float* __restrict__ D2p,
                                                        float* __restrict__ D1n,
                                                        float* __restrict__ D2n,
                                                        float2* __restrict__ Wb,
                                                        float gamp, int firstIter)
{
  __shared__ float2 twl[256];
  __shared__ float aL[5][256];
  __shared__ float bL[5][256];
  __shared__ float2 bufA[4][256];
  __shared__ float2 bufB[4][256];
  int t = threadIdx.x;
  make_tw(twl, t);
  int n = blockIdx.x >> 6;
  int r0 = (blockIdx.x & 63) << 2;
  const float* xn = x + (size_t)n * HWSZ;
  for (int rr = 0; rr < 5; ++rr) {
    int i = (r0 + rr) & 255;
    int im1 = (i - 1) & 255;
    int j = t;
    int jm1 = (j - 1) & 255;
    float xc = xn[(size_t)i * NSZ + j];
    float a, b;
    if (firstIter) {
      a = xc; b = xc;
    } else {
      float dhr = xc - xn[(size_t)i * NSZ + jm1];
      float dvr = xc - xn[(size_t)im1 * NSZ + j];
      size_t idx = (size_t)n * HWSZ + (size_t)i * NSZ + j;
      float d1 = D1p[idx], d2 = D2p[idx];
      float nu1 = dhr + d1, nu2 = dvr + d2;
      float nu = sqrtf(nu1 * nu1 + nu2 * nu2 + 1e-8f);
      float A = fmaxf(0.f, nu - gamp) + 1e-8f;
      A = A / (A + gamp);
      float u1 = A * nu1, u2 = A * nu2;
      float d1v = d1 + dhr - u1;
      float d2v = d2 + dvr - u2;
      if (rr < 4) { D1n[idx] = d1v; D2n[idx] = d2v; }
      a = u1 - d1v; b = u2 - d2v;
    }
    aL[rr][j] = a;
    bL[rr][j] = b;
  }
  __syncthreads();
  int w = t >> 6, lane = t & 63;
#pragma unroll
  for (int q = 0; q < 4; ++q) {
    int j = lane + (q << 6);
    int jp1 = (j + 1) & 255;
    float g = aL[w][j] - aL[w][jp1] + bL[w][j] - bL[w + 1][j];
    bufA[w][j] = make_float2(g, 0.f);
  }
  fft256(bufA[w], bufB[w], twl, lane, -1.f);
  float2* dst = Wb + (size_t)n * HWSZ + (size_t)(r0 + w) * NSZ;
#pragma unroll
  for (int q = 0; q < 4; ++q) { int j = lane + (q << 6); dst[j] = bufA[w][j]; }
}

__global__ __launch_bounds__(256) void k_colphase(float2* __restrict__ Wb,
                                                  const float2* __restrict__ FkF,
                                                  const float* __restrict__ fkr,
                                                  const float* __restrict__ fki,
                                                  const float* __restrict__ denq)
{
  __shared__ float2 twl[256];
  __shared__ float2 bufA[4][256];
  __shared__ float2 bufB[4][256];
  __shared__ double2 Mll[2][128];
  int t = threadIdx.x;
  make_tw(twl, t);
  int n = blockIdx.x >> 6;
  int j0 = (blockIdx.x & 63) << 1;
  int w = t >> 6, lane = t & 63;
  int gcw = j0 + (w & 1) + ((w >> 1) << 7);
  float2* Wn = Wb + (size_t)n * HWSZ;
#pragma unroll
  for (int q = 0; q < 4; ++q) { int u = lane + (q << 6); bufA[w][u] = Wn[(size_t)u * NSZ + gcw]; }
  fft256(bufA[w], bufB[w], twl, lane, -1.f);
#pragma unroll
  for (int c = 0; c < 4; ++c) {
    int u = t;
    int gc = j0 + (c & 1) + ((c >> 1) << 7);
    size_t idx = (size_t)n * HWSZ + (size_t)u * NSZ + gc;
    float2 kf = FkF[idx];
    float2 fg = bufA[c][u];
    bufA[c][u] = make_float2(kf.x + 1e-6f * fg.x, kf.y + 1e-6f * fg.y);
  }
  __syncthreads();
  {
    int u0 = t & 127, p = t >> 7;
    double sx = 0.0, sy = 0.0;
#pragma unroll
    for (int s = 0; s < 4; ++s) {
      int u = u0 + ((s & 1) << 7);
      int c = p + ((s >> 1) << 1);
      int gc = j0 + (c & 1) + ((c >> 1) << 7);
      size_t idx = (size_t)n * HWSZ + (size_t)u * NSZ + gc;
      float2 f1 = bufA[c][u];
      double kr = fkr[idx], ki = fki[idx];
      double fd2 = fdval(twl, u) + fdval(twl, gc) + 1e-8;
      sx += (kr * (double)f1.x - ki * (double)f1.y) / fd2;
      sy += (kr * (double)f1.y + ki * (double)f1.x) / fd2;
    }
    Mll[p][u0] = make_double2(sx * 0.25, sy * 0.25);
  }
  __syncthreads();
#pragma unroll
  for (int c = 0; c < 4; ++c) {
    int u = t;
    int gc = j0 + (c & 1) + ((c >> 1) << 7);
    size_t idx = (size_t)n * HWSZ + (size_t)u * NSZ + gc;
    float2 f1 = bufA[c][u];
    double2 m = Mll[c & 1][u & 127];
    double den = (double)denq[(size_t)n * 16384 + (size_t)(u & 127) * 128 + (j0 + (c & 1))];
    double kr = fkr[idx], ki = fki[idx];
    double px = (kr * m.x + ki * m.y) / den;
    double py = (kr * m.y - ki * m.x) / den;
    double fd2 = fdval(twl, u) + fdval(twl, gc) + 1e-8;
    double s2 = 1.0 / (1e-6 * fd2);
    bufA[c][u] = make_float2((float)(((double)f1.x - px) * s2),
                             (float)(((double)f1.y - py) * s2));
  }
  fft256(bufA[w], bufB[w], twl, lane, +1.f);
#pragma unroll
  for (int q = 0; q < 4; ++q) { int u = lane + (q << 6); Wn[(size_t)u * NSZ + gcw] = bufA[w][u]; }
}

__global__ __launch_bounds__(256) void k_rowinv(const float2* __restrict__ Wb,
                                                float* __restrict__ xout,
                                                const float* __restrict__ xold,
                                                float* __restrict__ pred,
                                                float cmom, int isLast)
{
  __shared__ float2 twl[256];
  __shared__ float2 bufA[4][256];
  __shared__ float2 bufB[4][256];
  int t = threadIdx.x;
  make_tw(twl, t);
  int n = blockIdx.x >> 6;
  int r0 = (blockIdx.x & 63) << 2;
  int w = t >> 6, lane = t & 63;
  const float2* src = Wb + (size_t)n * HWSZ + (size_t)(r0 + w) * NSZ;
#pragma unroll
  for (int q = 0; q < 4; ++q) { int j = lane + (q << 6); bufA[w][j] = src[j]; }
  fft256(bufA[w], bufB[w], twl, lane, +1.f);
  size_t base = (size_t)n * HWSZ + (size_t)(r0 + w) * NSZ;
#pragma unroll
  for (int q = 0; q < 4; ++q) {
    int j = lane + (q << 6);
    float v = bufA[w][j].x * (1.0f / 65536.0f);
    xout[base + j] = v;
    if (isLast) pred[base + j] = v + cmom * (v - xold[base + j]);
  }
}

// =======================================================================================
extern "C" void kernel_launch(void* const* d_in, const int* in_sizes, int n_in,
                              void* d_out, int out_size, void* d_ws, size_t ws_size,
                              hipStream_t stream)
{
  (void)in_sizes; (void)n_in; (void)out_size; (void)ws_size;
  const float* STy = (const float*)d_in[0];
  const float* fkr = (const float*)d_in[1];
  const float* fki = (const float*)d_in[2];
  float* out = (float*)d_out;

  char* p = (char*)d_ws;
  const size_t cplx = (size_t)NIMG * HWSZ * sizeof(float2);
  const size_t realb = (size_t)NIMG * HWSZ * sizeof(float);
  float2* WG  = (float2*)p; p += cplx;
  float2* WF  = (float2*)p; p += cplx;
  float2* FkF = (float2*)p; p += cplx;                          // fallback only
  float* denq = (float*)p;  p += (size_t)NIMG * 16384 * sizeof(float);  // fallback only
  float* D1a = (float*)p;   p += realb;                         // fallback only
  float* D2a = (float*)p;   p += realb;
  float* D1b = (float*)p;   p += realb;
  float* D2b = (float*)p;   p += realb;
  float* xA  = (float*)p;   p += realb;   // mega: x49 ; fallback: x0
  float* xB  = (float*)p;   p += realb;   // fallback: x1
  float* Dh  = (float*)p;   p += (size_t)2 * NBLK * 512 * sizeof(float);  // mega D halo
  unsigned* flags = (unsigned*)p; p += 4096;

  // host-side FISTA t sequence -> final momentum coefficient
  double t_old = 1.0, cm = 0.0;
  for (int k = 0; k < 50; ++k) {
    double t_new = (1.0 + sqrt(1.0 + 4.0 * t_old * t_old)) * 0.5;
    if (k == 49) cm = (t_old - 1.0) / t_new;
    t_old = t_new;
  }

  int maxb = 0;
  hipError_t oe = hipOccupancyMaxActiveBlocksPerMultiprocessor(&maxb, k_mega, 256, 0);
  bool coop = (oe == hipSuccess && maxb >= 3);

  dim3 grid(NBLK), blk(256);
  if (coop) {
    hipMemsetAsync(Dh, 0, (size_t)2 * NBLK * 512 * sizeof(float), stream);
    hipMemsetAsync(flags, 0, 4096, stream);
    k_mega<<<grid, blk, 0, stream>>>(STy, fkr, fki, WG, WF, Dh, xA, out, (float)cm, flags);
  } else {
    // proven round-0 path
    hipMemsetAsync(D1a, 0, 2 * realb, stream);
    float2* Wb = WG;
    float* x0 = xA; float* x1 = xB;
    k_rowfwd_sty<<<grid, blk, 0, stream>>>(STy, Wb);
    k_colsetup<<<grid, blk, 0, stream>>>(Wb, FkF, fkr, fki, denq);
    k_rowinv<<<grid, blk, 0, stream>>>(Wb, x0, x0, out, 0.f, 0);
    double to = 1.0;
    for (int k = 0; k < 50; ++k) {
      float gamp = (k >= 1) ? (float)(0.1 * exp2(-(double)(k - 1) / 50.0)) : 0.f;
      const float* xk = (k & 1) ? x1 : x0;
      float* xn = (k & 1) ? x0 : x1;
      const float* D1p = (k & 1) ? D1a : D1b;
      const float* D2p = (k & 1) ? D2a : D2b;
      float* D1w = (k & 1) ? D1b : D1a;
      float* D2w = (k & 1) ? D2b : D2a;
      k_spatial_rowfwd<<<grid, blk, 0, stream>>>(xk, D1p, D2p, D1w, D2w, Wb, gamp, (k == 0) ? 1 : 0);
      k_colphase<<<grid, blk, 0, stream>>>(Wb, FkF, fkr, fki, denq);
      double tn = (1.0 + sqrt(1.0 + 4.0 * to * to)) * 0.5;
      int isLast = (k == 49) ? 1 : 0;
      float cmom = (float)((to - 1.0) / tn);
      k_rowinv<<<grid, blk, 0, stream>>>(Wb, xn, xk, out, isLast ? cmom : 0.f, isLast);
      to = tn;
    }
  }
}